// Round 1
// 1431.400 us; speedup vs baseline: 1.1089x; 1.1089x over previous
//
#include <hip/hip_runtime.h>

#define Nb 256
#define Tt 512
#define Dd 64
#define TD (Tt * Dd)

__device__ __forceinline__ float sigmoidf_(float x) { return 1.0f / (1.0f + __expf(-x)); }
__device__ __forceinline__ float tanhf_(float x) {
    x = fminf(fmaxf(x, -15.0f), 15.0f);
    float e = __expf(2.0f * x);
    return (e - 1.0f) / (e + 1.0f);
}
// Barrier that drains ONLY LDS (cross-wave data is LDS-only here).
__device__ __forceinline__ void bar_lds() {
    asm volatile("s_waitcnt lgkmcnt(0)\n\ts_barrier" ::: "memory");
}
// broadcast lane k's value to all lanes via SGPR (no LDS pipe traffic)
__device__ __forceinline__ float lanebc(float v, int k) {
    return __int_as_float(__builtin_amdgcn_readlane(__float_as_int(v), k));
}
// dot-product accumulate: vector lives lane-distributed in vreg (lane k = v[k]),
// weights per-lane in w[]. Same k%4 accumulator interleave as the old float4 path.
__device__ __forceinline__ void rlacc(float& a0, float& a1, float& a2, float& a3,
                                      float v, const float* __restrict__ w) {
#pragma unroll
    for (int k = 0; k < 64; k += 4) {
        a0 = fmaf(lanebc(v, k + 0), w[k + 0], a0);
        a1 = fmaf(lanebc(v, k + 1), w[k + 1], a1);
        a2 = fmaf(lanebc(v, k + 2), w[k + 2], a2);
        a3 = fmaf(lanebc(v, k + 3), w[k + 3], a3);
    }
}
__device__ __forceinline__ void wait_flag(int* f, int want) {
    while (__hip_atomic_load(f, __ATOMIC_ACQUIRE, __HIP_MEMORY_SCOPE_WORKGROUP) < want) {}
    __builtin_amdgcn_sched_barrier(0);   // don't hoist dependent LDS reads above the poll
}
__device__ __forceinline__ void set_flag(int* f, int val) {
    asm volatile("s_waitcnt lgkmcnt(0)" ::: "memory");  // prior LDS writes committed
    __hip_atomic_store(f, val, __ATOMIC_RELEASE, __HIP_MEMORY_SCOPE_WORKGROUP);
}

// One block per batch row. 4 waves, weights register/AGPR-resident.
// Per step: ONE s_barrier (h hand-off). Intra-step deps via LDS flags:
//   w0: stage inputs(t+1), x_hat -> x_c  --fxc-->  w2: z_hat -> c_hat -> c_c --fcc--> all
//   w1: gamma_h(t+1), w3: beta(t+1) in their wait bubble (input-only deps).
__global__ __launch_bounds__(256, 1) void rits_kernel(
    const float* __restrict__ inp,
    const float* __restrict__ W_hist, const float* __restrict__ b_hist,
    const float* __restrict__ W_feat, const float* __restrict__ b_feat,
    const float* __restrict__ W_gx,   const float* __restrict__ b_gx,
    const float* __restrict__ W_gh,   const float* __restrict__ b_gh,
    const float* __restrict__ W_beta, const float* __restrict__ b_beta,
    const float* __restrict__ W_lstm, const float* __restrict__ U_lstm,
    const float* __restrict__ b_lstm,
    const float* __restrict__ W_out,  const float* __restrict__ b_out,
    float* __restrict__ out)
{
    __shared__ __align__(16) float s_h[2][64];
    __shared__ __align__(16) float s_m[2][64];
    __shared__ __align__(16) float s_x[2][64];
    __shared__ __align__(16) float s_d[2][64];
    __shared__ __align__(16) float s_gx[2][64];
    __shared__ __align__(16) float s_gh[2][64];
    __shared__ __align__(16) float s_bt[2][64];
    __shared__ __align__(16) float s_xc[64];
    __shared__ __align__(16) float s_xh[64];
    __shared__ __align__(16) float s_cc[64];
    __shared__ int s_fstage;   // staged-through step index + 1
    __shared__ int s_fxc;      // x_c for step t ready  (value t+1)
    __shared__ int s_fcc;      // c_c for step t ready  (value t+1)

    const int tid  = threadIdx.x;
    const int wave = tid >> 6;
    const int j    = tid & 63;
    const int jl   = j & 15;
    const int gate = j >> 4;
    const int n    = blockIdx.x;
    const int col  = (gate << 6) + (wave << 4) + jl;

    // ---- register-resident weights (same layout as before) ----
    float wl[128], wu[64];
#pragma unroll
    for (int k = 0; k < 128; ++k) wl[k] = W_lstm[k * 256 + col];
#pragma unroll
    for (int k = 0; k < 64; ++k)  wu[k] = U_lstm[k * 256 + col];
    const float bl = b_lstm[col];

    const float* Wsel = (wave == 0) ? W_hist : (wave == 1) ? W_gh
                      : (wave == 2) ? W_feat : W_beta;
    float wA[64];
#pragma unroll
    for (int k = 0; k < 64; ++k)
        wA[k] = (wave == 2 && k == j) ? 0.0f : Wsel[k * 64 + j];  // zero-diag for W_feat
    float wB[64];
    if (wave == 3) {
#pragma unroll
        for (int k = 0; k < 64; ++k) wB[k] = W_beta[(64 + k) * 64 + j];
    } else {
#pragma unroll
        for (int k = 0; k < 64; ++k) wB[k] = 0.0f;
    }
    const float bwv = (wave == 0) ? b_hist[j] : (wave == 1) ? b_gh[j]
                    : (wave == 2) ? b_feat[j] : b_beta[j];

    float gxw = 0, gxb = 0, wout = 0, bo = 0;
    if (wave == 0) {
        gxw = W_gx[j * 64 + j]; gxb = b_gx[j];
        wout = W_out[j]; bo = b_out[0];
    }

    const size_t base = (size_t)n * (3 * TD);
    float cx = 0, cm = 0, nx = 0, nm = 0, nd = 0;
    float c = 0.0f;

    // ---- prologue: flags, h0, stage t=0, prefetch t=1 ----
    if (wave == 0) {
        s_fstage = 0; s_fxc = 0; s_fcc = 0;
        cx = inp[base + j]; cm = inp[base + TD + j];
        float cd = inp[base + 2 * TD + j];
        s_x[0][j] = cx; s_m[0][j] = cm; s_d[0][j] = cd;
        s_gx[0][j] = __expf(-fmaxf(fmaf(cd, gxw, gxb), 0.0f));
        nx = inp[base + Dd + j];
        nm = inp[base + TD + Dd + j];
        nd = inp[base + 2 * TD + Dd + j];
    } else if (wave == 1) {
        s_h[0][j] = 0.0f;
    }
    bar_lds();
    // gamma_h(0) and beta(0) from staged t=0 inputs
    if (wave == 1) {
        float a0 = 0, a1 = 0, a2 = 0, a3 = 0;
        rlacc(a0, a1, a2, a3, s_d[0][j], wA);
        s_gh[0][j] = __expf(-fmaxf(bwv + ((a0 + a1) + (a2 + a3)), 0.0f));
    } else if (wave == 3) {
        float a0 = 0, a1 = 0, a2 = 0, a3 = 0;
        rlacc(a0, a1, a2, a3, s_gx[0][j], wA);
        rlacc(a0, a1, a2, a3, s_m[0][j], wB);
        s_bt[0][j] = sigmoidf_(bwv + ((a0 + a1) + (a2 + a3)));
    }
    bar_lds();

#pragma unroll 1
    for (int t = 0; t < Tt; ++t) {
        const int buf = t & 1, nbuf = buf ^ 1;
        // lane-distributed vectors for this step (1 ds_read_b32 each)
        float hreg  = s_h[buf][j];
        float ghreg = s_gh[buf][j];
        float mreg  = s_m[buf][j];
        float z0 = 0, z1 = 0, z2 = 0, z3 = 0;

        if (wave == 0) {
            // x_hat first: unblocks wave 2's chain
            float a0 = 0, a1 = 0, a2 = 0, a3 = 0;
            rlacc(a0, a1, a2, a3, hreg, wA);
            float acc = bwv + ((a0 + a1) + (a2 + a3));
            s_xh[j] = acc;
            s_xc[j] = fmaf(cm, cx, (1.0f - cm) * acc);
            set_flag(&s_fxc, t + 1);
            out[(size_t)((n * 3 + 0) * Tt + t) * Dd + j] = acc;
            // stage t+1, prefetch t+2
            if (t + 1 < Tt) {
                s_x[nbuf][j] = nx; s_m[nbuf][j] = nm; s_d[nbuf][j] = nd;
                s_gx[nbuf][j] = __expf(-fmaxf(fmaf(nd, gxw, gxb), 0.0f));
                set_flag(&s_fstage, t + 2);
                cx = nx; cm = nm;
                if (t + 2 < Tt) {
                    nx = inp[base + (t + 2) * Dd + j];
                    nm = inp[base + TD + (t + 2) * Dd + j];
                    nd = inp[base + 2 * TD + (t + 2) * Dd + j];
                }
            }
        }

        // ---- common z partials: m-part + U-part (hp = h*gamma_h, per-lane) ----
        rlacc(z0, z1, z2, z3, mreg, wl + 64);
        rlacc(z0, z1, z2, z3, hreg * ghreg, wu);

        if (wave == 2) {
            wait_flag(&s_fxc, t + 1);
            float a0 = 0, a1 = 0, a2 = 0, a3 = 0;
            rlacc(a0, a1, a2, a3, s_xc[j], wA);
            float acc = bwv + ((a0 + a1) + (a2 + a3));
            float bt  = s_bt[buf][j];
            float chat = bt * acc + (1.0f - bt) * s_xh[j];
            float xj  = s_x[buf][j];
            float ccj = fmaf(mreg, xj, (1.0f - mreg) * chat);
            s_cc[j] = ccj;
            set_flag(&s_fcc, t + 1);
            out[(size_t)((n * 3 + 1) * Tt + t) * Dd + j] = acc;
            out[(size_t)((n * 3 + 2) * Tt + t) * Dd + j] = chat;
        } else if (wave == 1) {
            if (t + 1 < Tt) {  // gamma_h for t+1 (input-only dep) in the wait bubble
                wait_flag(&s_fstage, t + 2);
                float a0 = 0, a1 = 0, a2 = 0, a3 = 0;
                rlacc(a0, a1, a2, a3, s_d[nbuf][j], wA);
                s_gh[nbuf][j] = __expf(-fmaxf(bwv + ((a0 + a1) + (a2 + a3)), 0.0f));
            }
        } else if (wave == 3) {
            if (t + 1 < Tt) {  // beta for t+1 (input-only dep) in the wait bubble
                wait_flag(&s_fstage, t + 2);
                float a0 = 0, a1 = 0, a2 = 0, a3 = 0;
                rlacc(a0, a1, a2, a3, s_gx[nbuf][j], wA);
                rlacc(a0, a1, a2, a3, s_m[nbuf][j], wB);
                s_bt[nbuf][j] = sigmoidf_(bwv + ((a0 + a1) + (a2 + a3)));
            }
        }

        // ---- z finalize + in-wave LSTM ----
        wait_flag(&s_fcc, t + 1);
        rlacc(z0, z1, z2, z3, s_cc[j], wl);
        float z = bl + ((z0 + z1) + (z2 + z3));
        float zi = __shfl(z, jl, 64);
        float zf = __shfl(z, 16 + jl, 64);
        float zg = __shfl(z, 32 + jl, 64);
        float zo = __shfl(z, 48 + jl, 64);
        c = sigmoidf_(zf) * c + sigmoidf_(zi) * tanhf_(zg);
        float hn = sigmoidf_(zo) * tanhf_(c);
        if (gate == 0) s_h[nbuf][(wave << 4) + jl] = hn;
        bar_lds();   // the ONLY barrier per step: h/gh/bt/staged-input hand-off
    }

    // final prediction: sigmoid(h_last @ W_out + b_out)
    if (wave == 0) {
        float p = s_h[Tt & 1][j] * wout;
#pragma unroll
        for (int off = 32; off > 0; off >>= 1) p += __shfl_down(p, off, 64);
        if (j == 0) out[(size_t)Nb * 3 * TD + n] = sigmoidf_(p + bo);
    }
}

extern "C" void kernel_launch(void* const* d_in, const int* in_sizes, int n_in,
                              void* d_out, int out_size, void* d_ws, size_t ws_size,
                              hipStream_t stream) {
    (void)in_sizes; (void)n_in; (void)out_size; (void)d_ws; (void)ws_size;
    const float* inp    = (const float*)d_in[0];
    const float* W_hist = (const float*)d_in[1];
    const float* b_hist = (const float*)d_in[2];
    const float* W_feat = (const float*)d_in[3];
    const float* b_feat = (const float*)d_in[4];
    const float* W_gx   = (const float*)d_in[5];
    const float* b_gx   = (const float*)d_in[6];
    const float* W_gh   = (const float*)d_in[7];
    const float* b_gh   = (const float*)d_in[8];
    const float* W_beta = (const float*)d_in[9];
    const float* b_beta = (const float*)d_in[10];
    const float* W_lstm = (const float*)d_in[11];
    const float* U_lstm = (const float*)d_in[12];
    const float* b_lstm = (const float*)d_in[13];
    const float* W_out  = (const float*)d_in[14];
    const float* b_out  = (const float*)d_in[15];
    float* out = (float*)d_out;

    rits_kernel<<<dim3(Nb), dim3(256), 0, stream>>>(
        inp, W_hist, b_hist, W_feat, b_feat, W_gx, b_gx, W_gh, b_gh,
        W_beta, b_beta, W_lstm, U_lstm, b_lstm, W_out, b_out, out);
}